// Round 2
// baseline (145.430 us; speedup 1.0000x reference)
//
#include <hip/hip_runtime.h>
#include <math.h>

// Problem constants (from reference)
#define BB 16
#define NN 65536
#define DD 8
#define OUT_SIZE 4096
#define IN_SIZE 4096

#define BLOCKS_PER_B 32
#define NC (NN / BLOCKS_PER_B)        // 2048 tuples per block
#define BLOCK_THREADS 512             // 8 waves/block -> 2 blocks/CU co-resident
#define ITERS (NC / BLOCK_THREADS)    // 4 tuples per thread, register-pipelined

// y[b,o] = bias[o]  (output is re-poisoned before every timed launch)
__global__ void init_out(const float* __restrict__ bias, float* __restrict__ y) {
    int i = blockIdx.x * blockDim.x + threadIdx.x;     // 0 .. B*OUT_SIZE-1
    y[i] = bias[i & (OUT_SIZE - 1)];
}

// 512 threads, min 4 waves/EU => VGPR cap 128, 2 blocks/CU resident.
// Per thread: 4 tuples, depth-1 register prefetch. Scatter is UNCONDITIONAL
// ds_add per sample: per-thread duplicate oi across d hit successive DS
// instructions from the same lane (no conflict), cross-lane same-address
// collisions are birthday-rare (64 of 4096 bins), so the old O(D^2) VALU
// merge (~140 ops/tuple + 8 exec-mask branches) was pure VALU overhead.
__global__ __launch_bounds__(BLOCK_THREADS, 4)
void hyper_scatter(const float* __restrict__ x,
                   const float* __restrict__ means,
                   const float* __restrict__ sigmas,
                   const float* __restrict__ values,
                   const float* __restrict__ noise,
                   float* __restrict__ y) {
    __shared__ float ys[OUT_SIZE];   // per-(b,chunk) partial output, 16 KB
    __shared__ float xs[IN_SIZE];    // staged x[b,:], 16 KB

    const int b     = blockIdx.x / BLOCKS_PER_B;
    const int chunk = blockIdx.x % BLOCKS_PER_B;
    const int tid   = threadIdx.x;
    const float* xb = x + (size_t)b * IN_SIZE;

    // zero partial accumulator + stage x[b] (512 threads, 2 float4 each)
    ((float4*)ys)[tid]                 = make_float4(0.f, 0.f, 0.f, 0.f);
    ((float4*)ys)[tid + BLOCK_THREADS] = make_float4(0.f, 0.f, 0.f, 0.f);
    ((float4*)xs)[tid]                 = ((const float4*)xb)[tid];
    ((float4*)xs)[tid + BLOCK_THREADS] = ((const float4*)xb)[tid + BLOCK_THREADS];
    __syncthreads();

    const size_t base0 = (size_t)b * NN + (size_t)(chunk * NC + tid);

    // ---- prefetch iteration 0 (7 loads, 80 B, all in flight together) ----
    float2 mean  = ((const float2*)means)[base0];
    float  sigma = sigmas[base0];
    float  value = values[base0];
    const float4* np4_0 = (const float4*)(noise + base0 * (size_t)(DD * 2));
    float4 nz0 = np4_0[0], nz1 = np4_0[1], nz2 = np4_0[2], nz3 = np4_0[3];

    #pragma unroll
    for (int it = 0; it < ITERS; ++it) {
        // rotate prefetched inputs into working registers
        const float2 m   = mean;
        const float  sg  = sigma;
        const float  val = value;
        const float4 c0 = nz0, c1 = nz1, c2 = nz2, c3 = nz3;

        // ---- issue next iteration's loads NOW; they complete under the
        // compute/gather/atomic phase below (depth-1 software pipeline) ----
        if (it + 1 < ITERS) {
            const size_t nb = base0 + (size_t)((it + 1) * BLOCK_THREADS);
            mean  = ((const float2*)means)[nb];
            sigma = sigmas[nb];
            value = values[nb];
            const float4* q4 = (const float4*)(noise + nb * (size_t)(DD * 2));
            nz0 = q4[0]; nz1 = q4[1]; nz2 = q4[2]; nz3 = q4[3];
        }

        const float nr[DD * 2] = {
            c0.x, c0.y, c0.z, c0.w,
            c1.x, c1.y, c1.z, c1.w,
            c2.x, c2.y, c2.z, c2.w,
            c3.x, c3.y, c3.z, c3.w };

        const float neg_inv_2s2 = -0.5f / (sg * sg);
        float p[DD];
        int   oi[DD], ii[DD];
        float psum = 0.f;
        #pragma unroll
        for (int d = 0; d < DD; ++d) {
            // EXACT sample rounding: mul-then-add, no FMA contraction,
            // so rintf() flips the same half-integer cases as np.round.
            float s0 = __fadd_rn(__fmul_rn(nr[2 * d],     sg), m.x);
            float s1 = __fadd_rn(__fmul_rn(nr[2 * d + 1], sg), m.y);
            float d0 = s0 - m.x;                // reference's diff (post-roundtrip)
            float d1 = s1 - m.y;
            float q  = d0 * d0 + d1 * d1;
            float pd = __expf(q * neg_inv_2s2); // 1/(2πσ²) cancels in normalization
            p[d] = pd;
            psum += pd;
            oi[d] = (int)fminf(fmaxf(rintf(s0), 0.f), (float)(OUT_SIZE - 1));
            ii[d] = (int)fminf(fmaxf(rintf(s1), 0.f), (float)(IN_SIZE - 1));
        }
        const float wscale = val / psum;        // one divide per tuple

        // all 8 gathers issued together; pipe-split so the DS and TA/L1
        // units work concurrently (x[b] is 16 KB, cache-resident).
        float xv[DD];
        #pragma unroll
        for (int d = 0; d < DD; ++d)
            xv[d] = (d & 1) ? xb[ii[d]] : xs[ii[d]];

        // unconditional no-return LDS atomics; wscale*p matches the
        // reference's (value*prob) * x[i] association.
        #pragma unroll
        for (int d = 0; d < DD; ++d) {
            atomicAdd(&ys[oi[d]], (wscale * p[d]) * xv[d]);
        }
    }
    __syncthreads();

    // one HW fp atomic per output element per block (coalesced, cheap)
    float* yb = y + (size_t)b * OUT_SIZE;
    #pragma unroll
    for (int o = tid; o < OUT_SIZE; o += BLOCK_THREADS) {
        unsafeAtomicAdd(&yb[o], ys[o]);
    }
}

extern "C" void kernel_launch(void* const* d_in, const int* in_sizes, int n_in,
                              void* d_out, int out_size, void* d_ws, size_t ws_size,
                              hipStream_t stream) {
    const float* x      = (const float*)d_in[0];   // [B, IN_SIZE]
    const float* means  = (const float*)d_in[1];   // [B, N, 2]
    const float* sigmas = (const float*)d_in[2];   // [B, N]
    const float* values = (const float*)d_in[3];   // [B, N]
    const float* bias   = (const float*)d_in[4];   // [OUT_SIZE]
    const float* noise  = (const float*)d_in[5];   // [B, N, D, 2]
    float* y = (float*)d_out;                      // [B, OUT_SIZE]

    init_out<<<(BB * OUT_SIZE) / 256, 256, 0, stream>>>(bias, y);
    hyper_scatter<<<BB * BLOCKS_PER_B, BLOCK_THREADS, 0, stream>>>(
        x, means, sigmas, values, noise, y);
}

// Round 3
// 128.863 us; speedup vs baseline: 1.1286x; 1.1286x over previous
//
#include <hip/hip_runtime.h>
#include <math.h>

// Problem constants (from reference)
#define BB 16
#define NN 65536
#define DD 8
#define OUT_SIZE 4096
#define IN_SIZE 4096

#define BLOCKS_PER_B 64
#define NC (NN / BLOCKS_PER_B)        // 1024 tuples per block
#define BLOCK_THREADS 512             // 8 waves/block
#define ITERS (NC / BLOCK_THREADS)    // 2 tuples per thread

// y[b,o] = bias[o]  (output is re-poisoned before every timed launch)
__global__ void init_out(const float* __restrict__ bias, float* __restrict__ y) {
    int i = blockIdx.x * blockDim.x + threadIdx.x;     // 0 .. B*OUT_SIZE-1
    y[i] = bias[i & (OUT_SIZE - 1)];
}

// Occupancy-first structure (round-2 counters: VALUBusy 9.4%, HBM 12%,
// Occupancy 36% -> latency-bound, all pipes idle at 2 blocks/CU):
//  - ys only in LDS (16 KB/block); x gathered straight from global
//    (16 KB/batch, L1/L2-resident) so the DS pipe is reserved for the
//    atomics, which the round-1->2 A/B proved are on the critical path.
//  - __launch_bounds__(512, 8): VGPR cap 64 (measured use 32), 16 KB LDS
//    -> 4 blocks/CU = 32 waves = 100% nominal occupancy.
//  - duplicate-oi merge RESTORED: the 8 samples of a tuple cluster within
//    a few bins of their mean, and unmerged same-lane same-address LDS
//    RMW chains serialize (round 2: +12 us). Merge -> distinct addresses.
__global__ __launch_bounds__(BLOCK_THREADS, 8)
void hyper_scatter(const float* __restrict__ x,
                   const float* __restrict__ means,
                   const float* __restrict__ sigmas,
                   const float* __restrict__ values,
                   const float* __restrict__ noise,
                   float* __restrict__ y) {
    __shared__ float ys[OUT_SIZE];   // per-(b,chunk) partial output, 16 KB

    const int b     = blockIdx.x / BLOCKS_PER_B;
    const int chunk = blockIdx.x % BLOCKS_PER_B;
    const int tid   = threadIdx.x;
    const float* xb = x + (size_t)b * IN_SIZE;

    // zero partial accumulator (512 threads, 2 float4 each)
    ((float4*)ys)[tid]                 = make_float4(0.f, 0.f, 0.f, 0.f);
    ((float4*)ys)[tid + BLOCK_THREADS] = make_float4(0.f, 0.f, 0.f, 0.f);
    __syncthreads();

    const size_t base0 = (size_t)b * NN + (size_t)(chunk * NC + tid);

    // ---- prefetch iteration 0 (7 loads, 80 B, all in flight together) ----
    float2 mean  = ((const float2*)means)[base0];
    float  sigma = sigmas[base0];
    float  value = values[base0];
    const float4* np4_0 = (const float4*)(noise + base0 * (size_t)(DD * 2));
    float4 nz0 = np4_0[0], nz1 = np4_0[1], nz2 = np4_0[2], nz3 = np4_0[3];

    #pragma unroll
    for (int it = 0; it < ITERS; ++it) {
        // rotate prefetched inputs into working registers
        const float2 m   = mean;
        const float  sg  = sigma;
        const float  val = value;
        const float4 c0 = nz0, c1 = nz1, c2 = nz2, c3 = nz3;

        // issue next iteration's loads now; they complete under the
        // compute/gather/atomic phase below (depth-1 software pipeline)
        if (it + 1 < ITERS) {
            const size_t nb = base0 + (size_t)((it + 1) * BLOCK_THREADS);
            mean  = ((const float2*)means)[nb];
            sigma = sigmas[nb];
            value = values[nb];
            const float4* q4 = (const float4*)(noise + nb * (size_t)(DD * 2));
            nz0 = q4[0]; nz1 = q4[1]; nz2 = q4[2]; nz3 = q4[3];
        }

        const float nr[DD * 2] = {
            c0.x, c0.y, c0.z, c0.w,
            c1.x, c1.y, c1.z, c1.w,
            c2.x, c2.y, c2.z, c2.w,
            c3.x, c3.y, c3.z, c3.w };

        const float neg_inv_2s2 = -0.5f / (sg * sg);
        float p[DD];
        int   oi[DD], ii[DD];
        float psum = 0.f;
        #pragma unroll
        for (int d = 0; d < DD; ++d) {
            // EXACT sample rounding: mul-then-add, no FMA contraction,
            // so rintf() flips the same half-integer cases as np.round.
            float s0 = __fadd_rn(__fmul_rn(nr[2 * d],     sg), m.x);
            float s1 = __fadd_rn(__fmul_rn(nr[2 * d + 1], sg), m.y);
            float d0 = s0 - m.x;                // reference's diff (post-roundtrip)
            float d1 = s1 - m.y;
            float q  = d0 * d0 + d1 * d1;
            float pd = __expf(q * neg_inv_2s2); // 1/(2πσ²) cancels in normalization
            p[d] = pd;
            psum += pd;
            oi[d] = (int)fminf(fmaxf(rintf(s0), 0.f), (float)(OUT_SIZE - 1));
            ii[d] = (int)fminf(fmaxf(rintf(s1), 0.f), (float)(IN_SIZE - 1));
        }
        const float wscale = val / psum;        // one divide per tuple

        // all 8 gathers from global x[b] (cache-resident); DS pipe stays
        // free for the atomics below.
        float xv[DD];
        #pragma unroll
        for (int d = 0; d < DD; ++d)
            xv[d] = xb[ii[d]];

        float v[DD];
        #pragma unroll
        for (int d = 0; d < DD; ++d) v[d] = p[d] * xv[d];

        // merge duplicate oi within the 8 samples: removes same-lane
        // same-address LDS RMW chains (proven +12 us when removed).
        bool deadO[DD];
        deadO[0] = false;
        #pragma unroll
        for (int d = 1; d < DD; ++d) {
            bool found = false;
            #pragma unroll
            for (int j = 0; j < d; ++j) {
                bool mch = (!deadO[j]) && (oi[j] == oi[d]);
                if (mch) v[j] += v[d];
                found = found || mch;
            }
            deadO[d] = found;
        }
        #pragma unroll
        for (int d = 0; d < DD; ++d) {
            if (!deadO[d]) atomicAdd(&ys[oi[d]], wscale * v[d]);
        }
    }
    __syncthreads();

    // one HW fp atomic per output element per block (coalesced, cheap)
    float* yb = y + (size_t)b * OUT_SIZE;
    #pragma unroll
    for (int o = tid; o < OUT_SIZE; o += BLOCK_THREADS) {
        unsafeAtomicAdd(&yb[o], ys[o]);
    }
}

extern "C" void kernel_launch(void* const* d_in, const int* in_sizes, int n_in,
                              void* d_out, int out_size, void* d_ws, size_t ws_size,
                              hipStream_t stream) {
    const float* x      = (const float*)d_in[0];   // [B, IN_SIZE]
    const float* means  = (const float*)d_in[1];   // [B, N, 2]
    const float* sigmas = (const float*)d_in[2];   // [B, N]
    const float* values = (const float*)d_in[3];   // [B, N]
    const float* bias   = (const float*)d_in[4];   // [OUT_SIZE]
    const float* noise  = (const float*)d_in[5];   // [B, N, D, 2]
    float* y = (float*)d_out;                      // [B, OUT_SIZE]

    init_out<<<(BB * OUT_SIZE) / 256, 256, 0, stream>>>(bias, y);
    hyper_scatter<<<BB * BLOCKS_PER_B, BLOCK_THREADS, 0, stream>>>(
        x, means, sigmas, values, noise, y);
}

// Round 4
// 126.543 us; speedup vs baseline: 1.1493x; 1.0183x over previous
//
#include <hip/hip_runtime.h>
#include <math.h>

// Problem constants (from reference)
#define BB 16
#define NN 65536
#define DD 8
#define OUT_SIZE 4096
#define IN_SIZE 4096

#define BLOCKS_PER_B 64
#define NC (NN / BLOCKS_PER_B)        // 1024 tuples per block
#define BLOCK_THREADS 512             // 8 waves/block
#define ITERS (NC / BLOCK_THREADS)    // 2 tuples per thread

// y[b,o] = bias[o]  (output is re-poisoned before every timed launch)
__global__ void init_out(const float* __restrict__ bias, float* __restrict__ y) {
    int i = blockIdx.x * blockDim.x + threadIdx.x;     // 0 .. B*OUT_SIZE-1
    y[i] = bias[i & (OUT_SIZE - 1)];
}

// Round-4 structure: vmcnt/lgkmcnt DOMAIN SPLIT.
// vmcnt retires in issue order, so global x-gathers issued after the next
// iteration's HBM prefetch could not complete before the prefetch drained
// -> every iteration ate an un-hidden HBM latency (why rounds 0-3 all
// converged to ~35 us with every pipe idle). Fix: gather x exclusively
// from LDS (lgkmcnt domain). The only vmcnt wait left is the top-of-loop
// rotation, which sits behind a full tuple of compute.
//  - xs + ys = 32 KB LDS, 512 thr, launch_bounds(512,8): 4 blocks/CU
//    (128 KB LDS, 2048 thr) = 32 waves/CU nominal.
//  - duplicate-oi merge kept (round-2 A/B: removing it cost +12 us).
__global__ __launch_bounds__(BLOCK_THREADS, 8)
void hyper_scatter(const float* __restrict__ x,
                   const float* __restrict__ means,
                   const float* __restrict__ sigmas,
                   const float* __restrict__ values,
                   const float* __restrict__ noise,
                   float* __restrict__ y) {
    __shared__ float ys[OUT_SIZE];   // per-(b,chunk) partial output, 16 KB
    __shared__ float xs[IN_SIZE];    // staged x[b,:], 16 KB

    const int b     = blockIdx.x / BLOCKS_PER_B;
    const int chunk = blockIdx.x % BLOCKS_PER_B;
    const int tid   = threadIdx.x;
    const float* xb = x + (size_t)b * IN_SIZE;

    // zero partial accumulator + stage x[b] (512 threads, 2 float4 each)
    ((float4*)ys)[tid]                 = make_float4(0.f, 0.f, 0.f, 0.f);
    ((float4*)ys)[tid + BLOCK_THREADS] = make_float4(0.f, 0.f, 0.f, 0.f);
    ((float4*)xs)[tid]                 = ((const float4*)xb)[tid];
    ((float4*)xs)[tid + BLOCK_THREADS] = ((const float4*)xb)[tid + BLOCK_THREADS];
    __syncthreads();

    const size_t base0 = (size_t)b * NN + (size_t)(chunk * NC + tid);

    // ---- prefetch iteration 0 (7 loads, 80 B, all in flight together) ----
    float2 mean  = ((const float2*)means)[base0];
    float  sigma = sigmas[base0];
    float  value = values[base0];
    const float4* np4_0 = (const float4*)(noise + base0 * (size_t)(DD * 2));
    float4 nz0 = np4_0[0], nz1 = np4_0[1], nz2 = np4_0[2], nz3 = np4_0[3];

    #pragma unroll
    for (int it = 0; it < ITERS; ++it) {
        // rotate prefetched inputs into working registers
        const float2 m   = mean;
        const float  sg  = sigma;
        const float  val = value;
        const float4 c0 = nz0, c1 = nz1, c2 = nz2, c3 = nz3;

        // issue next iteration's streaming loads now; they are the ONLY
        // outstanding vmcnt ops, drained at the next rotation (covered by
        // a full tuple of compute + gathers + atomics in between).
        if (it + 1 < ITERS) {
            const size_t nb = base0 + (size_t)((it + 1) * BLOCK_THREADS);
            mean  = ((const float2*)means)[nb];
            sigma = sigmas[nb];
            value = values[nb];
            const float4* q4 = (const float4*)(noise + nb * (size_t)(DD * 2));
            nz0 = q4[0]; nz1 = q4[1]; nz2 = q4[2]; nz3 = q4[3];
        }

        const float nr[DD * 2] = {
            c0.x, c0.y, c0.z, c0.w,
            c1.x, c1.y, c1.z, c1.w,
            c2.x, c2.y, c2.z, c2.w,
            c3.x, c3.y, c3.z, c3.w };

        const float neg_inv_2s2 = -0.5f / (sg * sg);
        float p[DD];
        int   oi[DD], ii[DD];
        float psum = 0.f;
        #pragma unroll
        for (int d = 0; d < DD; ++d) {
            // EXACT sample rounding: mul-then-add, no FMA contraction,
            // so rintf() flips the same half-integer cases as np.round.
            float s0 = __fadd_rn(__fmul_rn(nr[2 * d],     sg), m.x);
            float s1 = __fadd_rn(__fmul_rn(nr[2 * d + 1], sg), m.y);
            float d0 = s0 - m.x;                // reference's diff (post-roundtrip)
            float d1 = s1 - m.y;
            float q  = d0 * d0 + d1 * d1;
            float pd = __expf(q * neg_inv_2s2); // 1/(2πσ²) cancels in normalization
            p[d] = pd;
            psum += pd;
            oi[d] = (int)fminf(fmaxf(rintf(s0), 0.f), (float)(OUT_SIZE - 1));
            ii[d] = (int)fminf(fmaxf(rintf(s1), 0.f), (float)(IN_SIZE - 1));
        }
        const float wscale = val / psum;        // one divide per tuple

        // ALL gathers from LDS: lgkmcnt domain, decoupled from the
        // streaming vmcnt queue. ~4-way random bank conflicts, ~10 cyc/op.
        float xv[DD];
        #pragma unroll
        for (int d = 0; d < DD; ++d)
            xv[d] = xs[ii[d]];

        float v[DD];
        #pragma unroll
        for (int d = 0; d < DD; ++d) v[d] = p[d] * xv[d];

        // merge duplicate oi within the 8 samples: removes same-lane
        // same-address LDS RMW chains (proven +12 us when removed).
        bool deadO[DD];
        deadO[0] = false;
        #pragma unroll
        for (int d = 1; d < DD; ++d) {
            bool found = false;
            #pragma unroll
            for (int j = 0; j < d; ++j) {
                bool mch = (!deadO[j]) && (oi[j] == oi[d]);
                if (mch) v[j] += v[d];
                found = found || mch;
            }
            deadO[d] = found;
        }
        #pragma unroll
        for (int d = 0; d < DD; ++d) {
            if (!deadO[d]) atomicAdd(&ys[oi[d]], wscale * v[d]);
        }
    }
    __syncthreads();

    // one HW fp atomic per output element per block (coalesced, cheap)
    float* yb = y + (size_t)b * OUT_SIZE;
    #pragma unroll
    for (int o = tid; o < OUT_SIZE; o += BLOCK_THREADS) {
        unsafeAtomicAdd(&yb[o], ys[o]);
    }
}

extern "C" void kernel_launch(void* const* d_in, const int* in_sizes, int n_in,
                              void* d_out, int out_size, void* d_ws, size_t ws_size,
                              hipStream_t stream) {
    const float* x      = (const float*)d_in[0];   // [B, IN_SIZE]
    const float* means  = (const float*)d_in[1];   // [B, N, 2]
    const float* sigmas = (const float*)d_in[2];   // [B, N]
    const float* values = (const float*)d_in[3];   // [B, N]
    const float* bias   = (const float*)d_in[4];   // [OUT_SIZE]
    const float* noise  = (const float*)d_in[5];   // [B, N, D, 2]
    float* y = (float*)d_out;                      // [B, OUT_SIZE]

    init_out<<<(BB * OUT_SIZE) / 256, 256, 0, stream>>>(bias, y);
    hyper_scatter<<<BB * BLOCKS_PER_B, BLOCK_THREADS, 0, stream>>>(
        x, means, sigmas, values, noise, y);
}